// Round 3
// baseline (235.347 us; speedup 1.0000x reference)
//
#include <hip/hip_runtime.h>
#include <hip/hip_bf16.h>

typedef unsigned short u16;
typedef unsigned int u32;
typedef __attribute__((ext_vector_type(8))) short bf16x8;   // 8 bf16 (4 VGPRs)
typedef __attribute__((ext_vector_type(4))) short s16x4;
typedef __attribute__((ext_vector_type(4))) float f32x4;

#define NN 4096

__device__ __forceinline__ u16 f2bf(float f) {
    union { float f; u32 u; } v; v.f = f;
    u32 r = v.u + 0x7fffu + ((v.u >> 16) & 1u);   // RNE (inputs finite)
    return (u16)(r >> 16);
}

// ---------------- K1: deg = rowsum(A); inv_d = 1/(deg+1) ----------------
__global__ void rowsum_kernel(const float* __restrict__ A, float* __restrict__ invd) {
    const int row = blockIdx.x;
    const float4* a4 = reinterpret_cast<const float4*>(A + (size_t)row * NN);
    float s = 0.f;
    #pragma unroll
    for (int i = 0; i < 4; ++i) {
        float4 v = a4[threadIdx.x + i * 256];
        s += v.x + v.y + v.z + v.w;
    }
    #pragma unroll
    for (int off = 32; off > 0; off >>= 1) s += __shfl_down(s, off, 64);
    __shared__ float ws[4];
    if ((threadIdx.x & 63) == 0) ws[threadIdx.x >> 6] = s;
    __syncthreads();
    if (threadIdx.x == 0) {
        float t = ws[0] + ws[1] + ws[2] + ws[3];
        invd[row] = 1.0f / (t + 1.0f);
    }
}

// ------- K2: temp = 0.5*h + 0.5*(A + I)*inv_d[col]  -> bf16 [M][K] -------
__global__ void make_temp_kernel(const float* __restrict__ A, const float* __restrict__ h,
                                 const float* __restrict__ invd, u16* __restrict__ T) {
    const size_t g = ((size_t)blockIdx.x * 256 + threadIdx.x) * 8;
    const int row = (int)(g >> 12);
    const int col = (int)(g & 4095);
    const float4* a4 = reinterpret_cast<const float4*>(A + g);
    const float4* h4 = reinterpret_cast<const float4*>(h + g);
    const float4* d4 = reinterpret_cast<const float4*>(invd + col);
    float4 a0 = a4[0], a1 = a4[1];
    float4 h0 = h4[0], h1 = h4[1];
    float4 dd0 = d4[0], dd1 = d4[1];
    float av[8] = {a0.x,a0.y,a0.z,a0.w,a1.x,a1.y,a1.z,a1.w};
    float hv[8] = {h0.x,h0.y,h0.z,h0.w,h1.x,h1.y,h1.z,h1.w};
    float dv[8] = {dd0.x,dd0.y,dd0.z,dd0.w,dd1.x,dd1.y,dd1.z,dd1.w};
    bf16x8 o;
    #pragma unroll
    for (int j = 0; j < 8; ++j) {
        float aa = av[j] + ((col + j == row) ? 1.0f : 0.0f);
        float t = 0.5f * hv[j] + 0.5f * aa * dv[j];
        o[j] = (short)f2bf(t);
    }
    *reinterpret_cast<bf16x8*>(T + g) = o;
}

// --------- K3: Wt[n][k] = bf16(W[k][n])  (LDS 64x64 tile transpose) ---------
__global__ void transposeW_kernel(const float* __restrict__ W, u16* __restrict__ Wt) {
    __shared__ float tile[64][65];
    const int nt = blockIdx.x & 63;
    const int kt = blockIdx.x >> 6;
    const int k0 = kt * 64, n0 = nt * 64;
    const int tr = threadIdx.x >> 4;          // 0..15
    const int tc = (threadIdx.x & 15) * 4;    // 0..60
    #pragma unroll
    for (int rr = 0; rr < 64; rr += 16) {
        float4 v = *reinterpret_cast<const float4*>(&W[(size_t)(k0 + tr + rr) * NN + n0 + tc]);
        tile[tr + rr][tc + 0] = v.x;
        tile[tr + rr][tc + 1] = v.y;
        tile[tr + rr][tc + 2] = v.z;
        tile[tr + rr][tc + 3] = v.w;
    }
    __syncthreads();
    #pragma unroll
    for (int rr = 0; rr < 64; rr += 16) {
        const int n = tr + rr;
        s16x4 o;
        #pragma unroll
        for (int j = 0; j < 4; ++j) o[j] = (short)f2bf(tile[tc + j][n]);
        *reinterpret_cast<s16x4*>(&Wt[(size_t)(n0 + n) * NN + k0 + tc]) = o;
    }
}

// ============ K4: C = temp[M][K] @ Wt[N][K]^T — 256x256 tile, BK=64, ============
// 8-phase (4 phases/K-tile x 2 dbuf), counted vmcnt(4), XOR swizzle, setprio.
// Region layout per buf: [A0 rows0-127][A1 rows128-255][B0 cols0-127][B1 cols128-255]
// each region = [128 rows][64 k] u16, swizzled: phys_kgrp = log_kgrp ^ ((row>>1)&7).

#define GLD16(g, l) __builtin_amdgcn_global_load_lds( \
    (const __attribute__((address_space(1))) void*)(g), \
    (__attribute__((address_space(3))) void*)(l), 16, 0, 0)

#define PHASE_MID  do { __builtin_amdgcn_sched_barrier(0); \
    __builtin_amdgcn_s_barrier(); asm volatile("" ::: "memory"); } while (0)
#define PHASE_END  do { __builtin_amdgcn_s_barrier(); \
    asm volatile("" ::: "memory"); } while (0)

__device__ __forceinline__ bf16x8 rd(const u16* base, int off, int ks) {
    const u16* p = base + off;
    if (ks) p = (const u16*)((uintptr_t)p ^ 64u);   // kslice1 = kgrp+4 -> XOR 64B
    return *reinterpret_cast<const bf16x8*>(p);
}

__global__ __launch_bounds__(512, 2) void gemm_kernel(
    const u16* __restrict__ Atl,   // [M][K] bf16 (temp)
    const u16* __restrict__ Btl,   // [N][K] bf16 (Wt)
    float* __restrict__ C)         // [M][N] f32
{
    __shared__ u16 S[2][4][8192];  // [buf][region][128*64] = 128 KiB

    const int tid  = threadIdx.x;
    const int wid  = tid >> 6;     // 0..7
    const int lane = tid & 63;
    const int llo  = lane & 15;
    const int lhi  = lane >> 4;    // 0..3
    const int wr   = wid >> 2;     // 0..1  (M half)
    const int wc   = wid & 3;      // 0..3  (N quarter)

    // XCD swizzle (grid=256, 256%8==0 -> bijective)
    const int swz = ((int)blockIdx.x & 7) * 32 + ((int)blockIdx.x >> 3);
    const int bm = swz >> 4, bn = swz & 15;
    const int tileRow = bm * 256, tileCol = bn * 256;

    // ---- staging addressing (inverse-swizzled global source, linear LDS dest)
    const int srow = tid >> 3;                               // 0..63
    const int skg  = (((tid & 7) ^ ((tid >> 4) & 7)) << 3);  // logical k offset
    const size_t R64  = (size_t)64 * NN;
    const size_t R128 = (size_t)128 * NN;
    const u16* pA = Atl + (size_t)(tileRow + srow) * NN + skg;
    const u16* pB = Btl + (size_t)(tileCol + srow) * NN + skg;
    u16* Sb = (u16*)&S[0][0][0];   // buf stride 32768, region stride 8192

    #define STAGE(src, dstbase) do { \
        GLD16((src), (dstbase) + tid * 8); \
        GLD16((src) + R64, (dstbase) + 4096 + tid * 8); } while (0)

    // ---- swizzled read offsets (ks=0; ks=1 via XOR 64B in rd()) ----
    int offA[8], offB[4];
    #pragma unroll
    for (int m = 0; m < 8; ++m) {
        const int row = m * 16 + llo;                        // row within A-region
        offA[m] = row * 64 + ((lhi ^ ((row >> 1) & 7)) << 3);
    }
    #pragma unroll
    for (int n = 0; n < 4; ++n) {
        const int row = (wc & 1) * 64 + n * 16 + llo;        // row within B-region
        offB[n] = row * 64 + ((lhi ^ ((row >> 1) & 7)) << 3);
    }

    f32x4 acc[8][4];
    #pragma unroll
    for (int m = 0; m < 8; ++m)
        #pragma unroll
        for (int n = 0; n < 4; ++n)
            acc[m][n] = (f32x4){0.f, 0.f, 0.f, 0.f};

    // ---- prologue: tile0 (A0,A1,B0,B1)->buf0, tile1 (B0,B1)->buf1 ----
    STAGE(pA,               Sb + 0 * 8192);
    STAGE(pA + R128,        Sb + 1 * 8192);
    STAGE(pB,               Sb + 2 * 8192);
    STAGE(pB + R128,        Sb + 3 * 8192);
    STAGE(pB + 64,          Sb + 32768 + 2 * 8192);
    STAGE(pB + R128 + 64,   Sb + 32768 + 3 * 8192);
    asm volatile("s_waitcnt vmcnt(4)" ::: "memory");   // tile0 landed
    __builtin_amdgcn_s_barrier();
    asm volatile("" ::: "memory");

    const u16* pAs = pA + 64;    // A source for tile g+1
    const u16* pBs = pB + 128;   // B source for tile g+2

    #pragma unroll 1
    for (int g = 0; g < 64; ++g) {
        u16* cb = Sb + (g & 1) * 32768;          // current buf (read; B stages)
        u16* nbuf = Sb + ((g + 1) & 1) * 32768;  // next buf (A stages)
        const u16* sAr = cb + wr * 8192;
        const u16* sBr = cb + (2 + (wc >> 1)) * 8192;

        // ================= phase 1: A[0..3] + B[0..1] reads | stage A0(g+1) =================
        bf16x8 a0[4][2], a1[4][2], b0[2][2], b1[2][2];
        #pragma unroll
        for (int m = 0; m < 4; ++m) { a0[m][0] = rd(sAr, offA[m], 0); a0[m][1] = rd(sAr, offA[m], 1); }
        #pragma unroll
        for (int n = 0; n < 2; ++n) { b0[n][0] = rd(sBr, offB[n], 0); b0[n][1] = rd(sBr, offB[n], 1); }
        if (g < 63) STAGE(pAs, nbuf + 0 * 8192);
        PHASE_MID;
        __builtin_amdgcn_s_setprio(1);
        #pragma unroll
        for (int ks = 0; ks < 2; ++ks)
            #pragma unroll
            for (int m = 0; m < 4; ++m)
                #pragma unroll
                for (int n = 0; n < 2; ++n)
                    acc[m][n] = __builtin_amdgcn_mfma_f32_16x16x32_bf16(a0[m][ks], b0[n][ks], acc[m][n], 0, 0, 0);
        __builtin_amdgcn_s_setprio(0);
        PHASE_END;

        // ================= phase 2: B[2..3] reads | stage A1(g+1) =================
        #pragma unroll
        for (int n = 0; n < 2; ++n) { b1[n][0] = rd(sBr, offB[2 + n], 0); b1[n][1] = rd(sBr, offB[2 + n], 1); }
        if (g < 63) STAGE(pAs + R128, nbuf + 1 * 8192);
        PHASE_MID;
        __builtin_amdgcn_s_setprio(1);
        #pragma unroll
        for (int ks = 0; ks < 2; ++ks)
            #pragma unroll
            for (int m = 0; m < 4; ++m)
                #pragma unroll
                for (int n = 0; n < 2; ++n)
                    acc[m][2 + n] = __builtin_amdgcn_mfma_f32_16x16x32_bf16(a0[m][ks], b1[n][ks], acc[m][2 + n], 0, 0, 0);
        __builtin_amdgcn_s_setprio(0);
        PHASE_END;

        // ================= phase 3: A[4..7] reads | stage B0(g+2) =================
        // B0(g) reads fully completed at phase-2 close -> safe to overwrite.
        #pragma unroll
        for (int m = 0; m < 4; ++m) { a1[m][0] = rd(sAr, offA[4 + m], 0); a1[m][1] = rd(sAr, offA[4 + m], 1); }
        if (g < 62) STAGE(pBs, cb + 2 * 8192);
        PHASE_MID;
        __builtin_amdgcn_s_setprio(1);
        #pragma unroll
        for (int ks = 0; ks < 2; ++ks)
            #pragma unroll
            for (int m = 0; m < 4; ++m)
                #pragma unroll
                for (int n = 0; n < 2; ++n)
                    acc[4 + m][n] = __builtin_amdgcn_mfma_f32_16x16x32_bf16(a1[m][ks], b0[n][ks], acc[4 + m][n], 0, 0, 0);
        __builtin_amdgcn_s_setprio(0);
        PHASE_END;

        // ================= phase 4: stage B1(g+2) | counted vmcnt =================
        if (g < 62) STAGE(pBs + R128, cb + 3 * 8192);
        if (g < 62)       asm volatile("s_waitcnt vmcnt(4)" ::: "memory");  // tile g+1 landed
        else if (g == 62) asm volatile("s_waitcnt vmcnt(0)" ::: "memory");  // drain for tile 63
        PHASE_MID;
        __builtin_amdgcn_s_setprio(1);
        #pragma unroll
        for (int ks = 0; ks < 2; ++ks)
            #pragma unroll
            for (int m = 0; m < 4; ++m)
                #pragma unroll
                for (int n = 0; n < 2; ++n)
                    acc[4 + m][2 + n] = __builtin_amdgcn_mfma_f32_16x16x32_bf16(a1[m][ks], b1[n][ks], acc[4 + m][2 + n], 0, 0, 0);
        __builtin_amdgcn_s_setprio(0);
        if (g < 63) PHASE_END;

        pAs += 64; pBs += 64;
    }

    // ---- epilogue: C/D layout col=lane&15, row=(lane>>4)*4+reg ----
    #pragma unroll
    for (int m = 0; m < 8; ++m) {
        #pragma unroll
        for (int n = 0; n < 4; ++n) {
            const size_t rbase = (size_t)(tileRow + wr * 128 + m * 16 + lhi * 4) * NN
                               + tileCol + wc * 64 + n * 16 + llo;
            #pragma unroll
            for (int j = 0; j < 4; ++j)
                C[rbase + (size_t)j * NN] = acc[m][n][j];
        }
    }
    #undef STAGE
}

// ---------------------------------------------------------------------------
extern "C" void kernel_launch(void* const* d_in, const int* in_sizes, int n_in,
                              void* d_out, int out_size, void* d_ws, size_t ws_size,
                              hipStream_t stream) {
    const float* A = (const float*)d_in[0];
    const float* h = (const float*)d_in[1];
    const float* W = (const float*)d_in[2];
    float* out = (float*)d_out;

    // workspace layout: inv_d (16KB) | temp bf16 (32MB) | Wt bf16 (32MB)
    float* invd = (float*)d_ws;
    u16* temp = (u16*)((char*)d_ws + 16384);
    u16* wt   = temp + (size_t)NN * NN;

    rowsum_kernel<<<NN, 256, 0, stream>>>(A, invd);
    make_temp_kernel<<<(NN * (size_t)NN) / (256 * 8), 256, 0, stream>>>(A, h, invd, temp);
    transposeW_kernel<<<(NN / 64) * (NN / 64), 256, 0, stream>>>(W, wt);
    gemm_kernel<<<256, 512, 0, stream>>>(temp, wt, out);
}

// Round 4
// 190.256 us; speedup vs baseline: 1.2370x; 1.2370x over previous
//
#include <hip/hip_runtime.h>
#include <hip/hip_bf16.h>

typedef unsigned short u16;
typedef unsigned int u32;
typedef __attribute__((ext_vector_type(8))) short bf16x8;   // 8 bf16 (4 VGPRs)
typedef __attribute__((ext_vector_type(4))) short s16x4;
typedef __attribute__((ext_vector_type(16))) float f32x16;

#define NN 4096

__device__ __forceinline__ u16 f2bf(float f) {
    union { float f; u32 u; } v; v.f = f;
    u32 r = v.u + 0x7fffu + ((v.u >> 16) & 1u);   // RNE (inputs finite)
    return (u16)(r >> 16);
}

// ---------------- K1: deg = rowsum(A); inv_d = 1/(deg+1) ----------------
__global__ void rowsum_kernel(const float* __restrict__ A, float* __restrict__ invd) {
    const int row = blockIdx.x;
    const float4* a4 = reinterpret_cast<const float4*>(A + (size_t)row * NN);
    float s = 0.f;
    #pragma unroll
    for (int i = 0; i < 4; ++i) {
        float4 v = a4[threadIdx.x + i * 256];
        s += v.x + v.y + v.z + v.w;
    }
    #pragma unroll
    for (int off = 32; off > 0; off >>= 1) s += __shfl_down(s, off, 64);
    __shared__ float ws[4];
    if ((threadIdx.x & 63) == 0) ws[threadIdx.x >> 6] = s;
    __syncthreads();
    if (threadIdx.x == 0) {
        float t = ws[0] + ws[1] + ws[2] + ws[3];
        invd[row] = 1.0f / (t + 1.0f);
    }
}

// ------- K2: temp = 0.5*h + 0.5*(A + I)*inv_d[col]  -> bf16 [M][K] -------
__global__ void make_temp_kernel(const float* __restrict__ A, const float* __restrict__ h,
                                 const float* __restrict__ invd, u16* __restrict__ T) {
    const size_t g = ((size_t)blockIdx.x * 256 + threadIdx.x) * 8;
    const int row = (int)(g >> 12);
    const int col = (int)(g & 4095);
    const float4* a4 = reinterpret_cast<const float4*>(A + g);
    const float4* h4 = reinterpret_cast<const float4*>(h + g);
    const float4* d4 = reinterpret_cast<const float4*>(invd + col);
    float4 a0 = a4[0], a1 = a4[1];
    float4 h0 = h4[0], h1 = h4[1];
    float4 dd0 = d4[0], dd1 = d4[1];
    float av[8] = {a0.x,a0.y,a0.z,a0.w,a1.x,a1.y,a1.z,a1.w};
    float hv[8] = {h0.x,h0.y,h0.z,h0.w,h1.x,h1.y,h1.z,h1.w};
    float dv[8] = {dd0.x,dd0.y,dd0.z,dd0.w,dd1.x,dd1.y,dd1.z,dd1.w};
    bf16x8 o;
    #pragma unroll
    for (int j = 0; j < 8; ++j) {
        float aa = av[j] + ((col + j == row) ? 1.0f : 0.0f);
        float t = 0.5f * hv[j] + 0.5f * aa * dv[j];
        o[j] = (short)f2bf(t);
    }
    *reinterpret_cast<bf16x8*>(T + g) = o;
}

// --------- K3: Wt[n][k] = bf16(W[k][n])  (LDS 64x64 tile transpose) ---------
__global__ void transposeW_kernel(const float* __restrict__ W, u16* __restrict__ Wt) {
    __shared__ float tile[64][65];
    const int nt = blockIdx.x & 63;
    const int kt = blockIdx.x >> 6;
    const int k0 = kt * 64, n0 = nt * 64;
    const int tr = threadIdx.x >> 4;          // 0..15
    const int tc = (threadIdx.x & 15) * 4;    // 0..60
    #pragma unroll
    for (int rr = 0; rr < 64; rr += 16) {
        float4 v = *reinterpret_cast<const float4*>(&W[(size_t)(k0 + tr + rr) * NN + n0 + tc]);
        tile[tr + rr][tc + 0] = v.x;
        tile[tr + rr][tc + 1] = v.y;
        tile[tr + rr][tc + 2] = v.z;
        tile[tr + rr][tc + 3] = v.w;
    }
    __syncthreads();
    #pragma unroll
    for (int rr = 0; rr < 64; rr += 16) {
        const int n = tr + rr;
        s16x4 o;
        #pragma unroll
        for (int j = 0; j < 4; ++j) o[j] = (short)f2bf(tile[tc + j][n]);
        *reinterpret_cast<s16x4*>(&Wt[(size_t)(n0 + n) * NN + k0 + tc]) = o;
    }
}

// ============ K4: C[M][N] = temp[M][K] @ Wt[N][K]^T (bf16 MFMA) ============
// R2 structure (proven 1040 TF): 256x256 tile, BK=32, 4 LDS buffers, 3-deep
// prefetch, counted vmcnt(8), XOR col-group swizzle, setprio.
// R4 change: mfma_f32_32x32x16_bf16 (8 ops/step/wave instead of 32 small).

#define GLD16(g, l) __builtin_amdgcn_global_load_lds( \
    (const __attribute__((address_space(1))) void*)(g), \
    (__attribute__((address_space(3))) void*)(l), 16, 0, 0)

__global__ __launch_bounds__(512, 2) void gemm_kernel(
    const u16* __restrict__ Atl,   // [M][K] bf16 (temp)
    const u16* __restrict__ Btl,   // [N][K] bf16 (Wt)
    float* __restrict__ C)         // [M][N] f32
{
    __shared__ u16 S[4][2][8192];  // [buf][A=0/B=1][256 rows x 32 k]

    const int tid  = threadIdx.x;
    const int wid  = tid >> 6;     // 0..7
    const int lane = tid & 63;
    const int l32  = lane & 31;
    const int lk   = lane >> 5;    // 0..1 (k-half selector)
    const int wr   = wid >> 2;     // 0..1  (M half: 128 rows)
    const int wc   = wid & 3;      // 0..3  (N quarter: 64 cols)

    // XCD swizzle (grid=256, 256%8==0 -> bijective)
    const int swz = ((int)blockIdx.x & 7) * 32 + ((int)blockIdx.x >> 3);
    const int bm = swz >> 4, bn = swz & 15;
    const int tileRow = bm * 256, tileCol = bn * 256;

    // ---- staging source addresses (inverse-swizzled; dest is linear) ----
    const int r0 = tid >> 2;
    const int kc = (((tid & 3) ^ ((r0 >> 1) & 3)) << 3);
    const u16* gA0 = Atl + (size_t)(tileRow + r0) * NN + kc;
    const u16* gA1 = gA0 + (size_t)128 * NN;
    const u16* gB0 = Btl + (size_t)(tileCol + r0) * NN + kc;
    const u16* gB1 = gB0 + (size_t)128 * NN;

    // ---- swizzled ds_read element offsets within S[b][x] ----
    // frag: row = base + (lane&31); logical kgrp = (lane>>5) + 2*ks
    // phys kgrp = logical ^ ((row>>1)&3); ks=1 == XOR 16 elements (32B)
    int offA[4][2], offB[2][2];
    #pragma unroll
    for (int mt = 0; mt < 4; ++mt) {
        const int row = wr * 128 + mt * 32 + l32;
        const int o0 = row * 32 + ((lk ^ ((row >> 1) & 3)) << 3);
        offA[mt][0] = o0; offA[mt][1] = o0 ^ 16;
    }
    #pragma unroll
    for (int nt = 0; nt < 2; ++nt) {
        const int row = wc * 64 + nt * 32 + l32;
        const int o0 = row * 32 + ((lk ^ ((row >> 1) & 3)) << 3);
        offB[nt][0] = o0; offB[nt][1] = o0 ^ 16;
    }

    f32x16 acc[4][2];
    #pragma unroll
    for (int mt = 0; mt < 4; ++mt)
        #pragma unroll
        for (int nt = 0; nt < 2; ++nt)
            #pragma unroll
            for (int j = 0; j < 16; ++j) acc[mt][nt][j] = 0.f;

    // ---- prologue: stage tiles 0,1,2 into buffers 0,1,2 ----
    #pragma unroll
    for (int p = 0; p < 3; ++p) {
        GLD16(gA0 + p * 32, &S[p][0][wid * 512]);
        GLD16(gA1 + p * 32, &S[p][0][4096 + wid * 512]);
        GLD16(gB0 + p * 32, &S[p][1][wid * 512]);
        GLD16(gB1 + p * 32, &S[p][1][4096 + wid * 512]);
    }
    gA0 += 96; gA1 += 96; gB0 += 96; gB1 += 96;
    asm volatile("s_waitcnt vmcnt(8)" ::: "memory");   // tile 0 landed
    __builtin_amdgcn_s_barrier();
    asm volatile("" ::: "memory");

    // ---- main loop: 128 K-steps of 32 ----
    #pragma unroll 1
    for (int t = 0; t < 128; ++t) {
        if (t < 125) {
            const int b3 = (t + 3) & 3;
            GLD16(gA0, &S[b3][0][wid * 512]);
            GLD16(gA1, &S[b3][0][4096 + wid * 512]);
            GLD16(gB0, &S[b3][1][wid * 512]);
            GLD16(gB1, &S[b3][1][4096 + wid * 512]);
            gA0 += 32; gA1 += 32; gB0 += 32; gB1 += 32;
        }
        __builtin_amdgcn_sched_barrier(0);   // pin stage-issue before compute

        const int b = t & 3;
        const u16* sA = &S[b][0][0];
        const u16* sB = &S[b][1][0];
        bf16x8 af[4][2], bv[2][2];
        #pragma unroll
        for (int mt = 0; mt < 4; ++mt) {
            af[mt][0] = *reinterpret_cast<const bf16x8*>(sA + offA[mt][0]);
            af[mt][1] = *reinterpret_cast<const bf16x8*>(sA + offA[mt][1]);
        }
        #pragma unroll
        for (int nt = 0; nt < 2; ++nt) {
            bv[nt][0] = *reinterpret_cast<const bf16x8*>(sB + offB[nt][0]);
            bv[nt][1] = *reinterpret_cast<const bf16x8*>(sB + offB[nt][1]);
        }

        __builtin_amdgcn_s_setprio(1);
        #pragma unroll
        for (int ks = 0; ks < 2; ++ks)
            #pragma unroll
            for (int mt = 0; mt < 4; ++mt)
                #pragma unroll
                for (int nt = 0; nt < 2; ++nt)
                    acc[mt][nt] = __builtin_amdgcn_mfma_f32_32x32x16_bf16(
                        af[mt][ks], bv[nt][ks], acc[mt][nt], 0, 0, 0);
        __builtin_amdgcn_s_setprio(0);

        // counted vmcnt: steps t and t-1 (8 instrs) may stay in flight.
        if (t < 125)       asm volatile("s_waitcnt vmcnt(8)" ::: "memory");
        else if (t == 125) asm volatile("s_waitcnt vmcnt(4)" ::: "memory");
        else if (t == 126) asm volatile("s_waitcnt vmcnt(0)" ::: "memory");
        if (t < 127) {
            __builtin_amdgcn_s_barrier();
            asm volatile("" ::: "memory");
        }
    }

    // ---- epilogue: 32x32 C/D layout col=lane&31, row=(reg&3)+8*(reg>>2)+4*(lane>>5)
    #pragma unroll
    for (int mt = 0; mt < 4; ++mt) {
        #pragma unroll
        for (int nt = 0; nt < 2; ++nt) {
            const size_t cbase = (size_t)(tileRow + wr * 128 + mt * 32 + 4 * lk) * NN
                               + tileCol + wc * 64 + nt * 32 + l32;
            #pragma unroll
            for (int reg = 0; reg < 16; ++reg) {
                const int rrow = (reg & 3) + 8 * (reg >> 2);
                C[cbase + (size_t)rrow * NN] = acc[mt][nt][reg];
            }
        }
    }
}

// ---------------------------------------------------------------------------
extern "C" void kernel_launch(void* const* d_in, const int* in_sizes, int n_in,
                              void* d_out, int out_size, void* d_ws, size_t ws_size,
                              hipStream_t stream) {
    const float* A = (const float*)d_in[0];
    const float* h = (const float*)d_in[1];
    const float* W = (const float*)d_in[2];
    float* out = (float*)d_out;

    // workspace layout: inv_d (16KB) | temp bf16 (32MB) | Wt bf16 (32MB)
    float* invd = (float*)d_ws;
    u16* temp = (u16*)((char*)d_ws + 16384);
    u16* wt   = temp + (size_t)NN * NN;

    rowsum_kernel<<<NN, 256, 0, stream>>>(A, invd);
    make_temp_kernel<<<(NN * (size_t)NN) / (256 * 8), 256, 0, stream>>>(A, h, invd, temp);
    transposeW_kernel<<<(NN / 64) * (NN / 64), 256, 0, stream>>>(W, wt);
    gemm_kernel<<<256, 512, 0, stream>>>(temp, wt, out);
}

// Round 5
// 168.221 us; speedup vs baseline: 1.3990x; 1.1310x over previous
//
#include <hip/hip_runtime.h>
#include <hip/hip_bf16.h>

typedef unsigned short u16;
typedef unsigned int u32;
typedef __attribute__((ext_vector_type(8))) short bf16x8;   // 8 bf16 (4 VGPRs)
typedef __attribute__((ext_vector_type(4))) short s16x4;
typedef __attribute__((ext_vector_type(4))) float f32x4;

#define NN 4096

__device__ __forceinline__ u16 f2bf(float f) {
    union { float f; u32 u; } v; v.f = f;
    u32 r = v.u + 0x7fffu + ((v.u >> 16) & 1u);   // RNE (inputs finite)
    return (u16)(r >> 16);
}

// ---------------- K1: deg = rowsum(A); inv_d = 1/(deg+1) ----------------
__global__ void rowsum_kernel(const float* __restrict__ A, float* __restrict__ invd) {
    const int row = blockIdx.x;
    const float4* a4 = reinterpret_cast<const float4*>(A + (size_t)row * NN);
    float s = 0.f;
    #pragma unroll
    for (int i = 0; i < 4; ++i) {
        float4 v = a4[threadIdx.x + i * 256];
        s += v.x + v.y + v.z + v.w;
    }
    #pragma unroll
    for (int off = 32; off > 0; off >>= 1) s += __shfl_down(s, off, 64);
    __shared__ float ws[4];
    if ((threadIdx.x & 63) == 0) ws[threadIdx.x >> 6] = s;
    __syncthreads();
    if (threadIdx.x == 0) {
        float t = ws[0] + ws[1] + ws[2] + ws[3];
        invd[row] = 1.0f / (t + 1.0f);
    }
}

// ------- K2: temp = 0.5*h + 0.5*(A + I)*inv_d[col]  -> bf16 [M][K] -------
__global__ void make_temp_kernel(const float* __restrict__ A, const float* __restrict__ h,
                                 const float* __restrict__ invd, u16* __restrict__ T) {
    const size_t g = ((size_t)blockIdx.x * 256 + threadIdx.x) * 8;
    const int row = (int)(g >> 12);
    const int col = (int)(g & 4095);
    const float4* a4 = reinterpret_cast<const float4*>(A + g);
    const float4* h4 = reinterpret_cast<const float4*>(h + g);
    const float4* d4 = reinterpret_cast<const float4*>(invd + col);
    float4 a0 = a4[0], a1 = a4[1];
    float4 h0 = h4[0], h1 = h4[1];
    float4 dd0 = d4[0], dd1 = d4[1];
    float av[8] = {a0.x,a0.y,a0.z,a0.w,a1.x,a1.y,a1.z,a1.w};
    float hv[8] = {h0.x,h0.y,h0.z,h0.w,h1.x,h1.y,h1.z,h1.w};
    float dv[8] = {dd0.x,dd0.y,dd0.z,dd0.w,dd1.x,dd1.y,dd1.z,dd1.w};
    bf16x8 o;
    #pragma unroll
    for (int j = 0; j < 8; ++j) {
        float aa = av[j] + ((col + j == row) ? 1.0f : 0.0f);
        float t = 0.5f * hv[j] + 0.5f * aa * dv[j];
        o[j] = (short)f2bf(t);
    }
    *reinterpret_cast<bf16x8*>(T + g) = o;
}

// --------- K3: Wt[n][k] = bf16(W[k][n])  (LDS 64x64 tile transpose) ---------
__global__ void transposeW_kernel(const float* __restrict__ W, u16* __restrict__ Wt) {
    __shared__ float tile[64][65];
    const int nt = blockIdx.x & 63;
    const int kt = blockIdx.x >> 6;
    const int k0 = kt * 64, n0 = nt * 64;
    const int tr = threadIdx.x >> 4;          // 0..15
    const int tc = (threadIdx.x & 15) * 4;    // 0..60
    #pragma unroll
    for (int rr = 0; rr < 64; rr += 16) {
        float4 v = *reinterpret_cast<const float4*>(&W[(size_t)(k0 + tr + rr) * NN + n0 + tc]);
        tile[tr + rr][tc + 0] = v.x;
        tile[tr + rr][tc + 1] = v.y;
        tile[tr + rr][tc + 2] = v.z;
        tile[tr + rr][tc + 3] = v.w;
    }
    __syncthreads();
    #pragma unroll
    for (int rr = 0; rr < 64; rr += 16) {
        const int n = tr + rr;
        s16x4 o;
        #pragma unroll
        for (int j = 0; j < 4; ++j) o[j] = (short)f2bf(tile[tc + j][n]);
        *reinterpret_cast<s16x4*>(&Wt[(size_t)(n0 + n) * NN + k0 + tc]) = o;
    }
}

// ============ K4: C[M][N] = temp[M][K] @ Wt[N][K]^T (bf16 MFMA) ============
// R5: 256x256 tile, BK=64, 2 LDS buffers, 1-deep prefetch with distance-
// justified vmcnt(0) (issue at step start, wait at step end, ~3300 cy apart),
// per-row XOR-8 swizzle for 128B rows, 64 steps / 64 barriers, setprio.

#define GLD16(g, l) __builtin_amdgcn_global_load_lds( \
    (const __attribute__((address_space(1))) void*)(g), \
    (__attribute__((address_space(3))) void*)(l), 16, 0, 0)

__global__ __launch_bounds__(512, 2) void gemm_kernel(
    const u16* __restrict__ Atl,   // [M][K] bf16 (temp)
    const u16* __restrict__ Btl,   // [N][K] bf16 (Wt)
    float* __restrict__ C)         // [M][N] f32
{
    __shared__ u16 S[2][2][16384]; // [buf][A=0/B=1][256 rows x 64 k] = 128 KiB

    const int tid  = threadIdx.x;
    const int wid  = tid >> 6;     // 0..7
    const int lane = tid & 63;
    const int llo  = lane & 15;
    const int lhi  = lane >> 4;    // 0..3
    const int wr   = wid >> 2;     // 0..1  (M half: 128 rows)
    const int wc   = wid & 3;      // 0..3  (N quarter: 64 cols)

    // XCD swizzle (grid=256, 256%8==0 -> bijective)
    const int swz = ((int)blockIdx.x & 7) * 32 + ((int)blockIdx.x >> 3);
    const int bm = swz >> 4, bn = swz & 15;
    const int tileRow = bm * 256, tileCol = bn * 256;

    // ---- staging: linear LDS dest, inverse-swizzled global source ----
    // LDS elem off (per region) = i*8192 + tid*8 -> row = i*128 + (tid>>3),
    // phys kgrp = tid&7. logical kgrp = (tid&7) ^ (row&7), row&7 = (tid>>3)&7.
    const int r0 = tid >> 3;                                // 0..63
    const int kc = (((tid & 7) ^ (r0 & 7)) << 3);           // logical k elem off
    const size_t R128 = (size_t)128 * NN;
    const u16* gA = Atl + (size_t)(tileRow + r0) * NN + kc;
    const u16* gB = Btl + (size_t)(tileCol + r0) * NN + kc;

    // per step: 4 A gld (rows 0/128 x i halves... i=0..3 -> row += 128 via +R128? no:
    // i covers 4x 64-row slabs: row = i*128+(tid>>3) is WRONG spacing; use i*64.
    // Correction: per gld instr (8KB) covers 64 rows (512 threads x 16B / 128B-row).
    // elem off = i*4096... recompute: region row stride 64 elems; 512 thr x 8 elems
    // = 4096 elems = 64 rows per instr. So row = i*64 + (tid>>3), i = 0..3.
    // (i*64)&7 == 0, swizzle formula unchanged.

    // ---- swizzled read offsets (elements) within a region ----
    // frag row r, logical kgrp lhi (ks0) / lhi+4 (ks1); phys = logical ^ (r&7).
    // ks1 offset = ks0 ^ 32 elements.
    int offA[8], offB[4];
    #pragma unroll
    for (int m = 0; m < 8; ++m) {
        const int row = wr * 128 + m * 16 + llo;
        offA[m] = row * 64 + ((lhi ^ (row & 7)) << 3);
    }
    #pragma unroll
    for (int n = 0; n < 4; ++n) {
        const int row = wc * 64 + n * 16 + llo;
        offB[n] = row * 64 + ((lhi ^ (row & 7)) << 3);
    }

    f32x4 acc[8][4];
    #pragma unroll
    for (int m = 0; m < 8; ++m)
        #pragma unroll
        for (int n = 0; n < 4; ++n)
            acc[m][n] = (f32x4){0.f, 0.f, 0.f, 0.f};

    #define STAGE_TILE(buf, koff) do { \
        _Pragma("unroll") \
        for (int i = 0; i < 4; ++i) { \
            GLD16(gA + (size_t)(i * 64) * NN + (koff), &S[buf][0][i * 4096 + tid * 8]); \
            GLD16(gB + (size_t)(i * 64) * NN + (koff), &S[buf][1][i * 4096 + tid * 8]); \
        } } while (0)

    // ---- prologue: stage tile 0 into buf 0 ----
    STAGE_TILE(0, 0);
    asm volatile("s_waitcnt vmcnt(0)" ::: "memory");
    __builtin_amdgcn_s_barrier();
    asm volatile("" ::: "memory");

    // ---- main loop: 64 K-steps of 64 ----
    #pragma unroll 1
    for (int t = 0; t < 64; ++t) {
        // stage tile t+1 into the other buffer (its reads finished at step t-1)
        if (t < 63) STAGE_TILE((t + 1) & 1, (t + 1) * 64);
        __builtin_amdgcn_sched_barrier(0);   // pin stage-issue before compute

        const u16* sA = &S[t & 1][0][0];
        const u16* sB = &S[t & 1][1][0];

        bf16x8 bv[4][2], af[8];
        #pragma unroll
        for (int n = 0; n < 4; ++n) {
            bv[n][0] = *reinterpret_cast<const bf16x8*>(sB + offB[n]);
            bv[n][1] = *reinterpret_cast<const bf16x8*>(sB + (offB[n] ^ 32));
        }
        #pragma unroll
        for (int m = 0; m < 8; ++m)
            af[m] = *reinterpret_cast<const bf16x8*>(sA + offA[m]);

        __builtin_amdgcn_s_setprio(1);
        #pragma unroll
        for (int m = 0; m < 8; ++m)
            #pragma unroll
            for (int n = 0; n < 4; ++n)
                acc[m][n] = __builtin_amdgcn_mfma_f32_16x16x32_bf16(
                    af[m], bv[n][0], acc[m][n], 0, 0, 0);
        __builtin_amdgcn_s_setprio(0);

        #pragma unroll
        for (int m = 0; m < 8; ++m)
            af[m] = *reinterpret_cast<const bf16x8*>(sA + (offA[m] ^ 32));

        __builtin_amdgcn_s_setprio(1);
        #pragma unroll
        for (int m = 0; m < 8; ++m)
            #pragma unroll
            for (int n = 0; n < 4; ++n)
                acc[m][n] = __builtin_amdgcn_mfma_f32_16x16x32_bf16(
                    af[m], bv[n][1], acc[m][n], 0, 0, 0);
        __builtin_amdgcn_s_setprio(0);

        // loads for tile t+1 were issued a full step (~3300 cy) ago -> ~free
        if (t < 63) {
            asm volatile("s_waitcnt vmcnt(0)" ::: "memory");
            __builtin_amdgcn_s_barrier();
            asm volatile("" ::: "memory");
        }
    }
    #undef STAGE_TILE

    // ---- epilogue: C/D layout col=lane&15, row=(lane>>4)*4+reg ----
    #pragma unroll
    for (int m = 0; m < 8; ++m) {
        #pragma unroll
        for (int n = 0; n < 4; ++n) {
            const size_t rbase = (size_t)(tileRow + wr * 128 + m * 16 + lhi * 4) * NN
                               + tileCol + wc * 64 + n * 16 + llo;
            #pragma unroll
            for (int j = 0; j < 4; ++j)
                C[rbase + (size_t)j * NN] = acc[m][n][j];
        }
    }
}

// ---------------------------------------------------------------------------
extern "C" void kernel_launch(void* const* d_in, const int* in_sizes, int n_in,
                              void* d_out, int out_size, void* d_ws, size_t ws_size,
                              hipStream_t stream) {
    const float* A = (const float*)d_in[0];
    const float* h = (const float*)d_in[1];
    const float* W = (const float*)d_in[2];
    float* out = (float*)d_out;

    // workspace layout: inv_d (16KB) | temp bf16 (32MB) | Wt bf16 (32MB)
    float* invd = (float*)d_ws;
    u16* temp = (u16*)((char*)d_ws + 16384);
    u16* wt   = temp + (size_t)NN * NN;

    rowsum_kernel<<<NN, 256, 0, stream>>>(A, invd);
    make_temp_kernel<<<(NN * (size_t)NN) / (256 * 8), 256, 0, stream>>>(A, h, invd, temp);
    transposeW_kernel<<<(NN / 64) * (NN / 64), 256, 0, stream>>>(W, wt);
    gemm_kernel<<<256, 512, 0, stream>>>(temp, wt, out);
}